// Round 1
// baseline (1854.659 us; speedup 1.0000x reference)
//
#include <hip/hip_runtime.h>

// Problem: T=1024, B=256, I=256, H=256, fp32.
// out layout: outputs [T,B,H] flat (T*B*H) followed by final state [B,H].
//
// Kernel A: XW = X @ W_xh + b_h written straight into out[0..T*B*H)
//   (XW has exactly the outputs' shape -> no workspace needed).
// Kernel B: per-batch-row recurrence; block b owns batch row b, keeps
//   W_hh column chunks in registers, state in LDS; reads xw from out,
//   overwrites out[t,b,:] with tanh state in place.

#define TT 1024
#define BB 256
#define HH 256

// ---------------- Kernel A: [262144,256] @ [256,256] + bias ----------------
// tile: 64 rows x 256 cols, K in chunks of 16. 256 threads, 8x8 micro-tile.
__global__ __launch_bounds__(256) void xw_gemm(const float* __restrict__ X,
                                               const float* __restrict__ W,
                                               const float* __restrict__ bh,
                                               float* __restrict__ out) {
    __shared__ float As[16][68];   // As[k][m], padded stride 68 (16B aligned, kills staging conflicts)
    __shared__ float Bs[16][256];  // Bs[k][n]

    const int tid = threadIdx.x;
    const int r0  = blockIdx.x * 64;
    const int tx  = tid & 31;   // col group: cols tx*8 .. tx*8+7
    const int ty  = tid >> 5;   // row group: rows ty*8 .. ty*8+7

    // staging index helpers
    const int m_l = tid >> 2;          // 0..63 (X row within tile)
    const int kv  = (tid & 3) * 4;     // 0,4,8,12 (X k offset)
    const int nw  = (tid & 63) * 4;    // W col
    const int kw  = tid >> 6;          // 0..3 (W k row)

    float acc[8][8];
#pragma unroll
    for (int i = 0; i < 8; i++)
#pragma unroll
        for (int j = 0; j < 8; j++) acc[i][j] = 0.f;

    for (int kc = 0; kc < 256; kc += 16) {
        // fetch to registers (no LDS dependence yet)
        float4 xv  = *(const float4*)(X + (size_t)(r0 + m_l) * 256 + kc + kv);
        float4 wv0 = *(const float4*)(W + (size_t)(kc + kw +  0) * 256 + nw);
        float4 wv1 = *(const float4*)(W + (size_t)(kc + kw +  4) * 256 + nw);
        float4 wv2 = *(const float4*)(W + (size_t)(kc + kw +  8) * 256 + nw);
        float4 wv3 = *(const float4*)(W + (size_t)(kc + kw + 12) * 256 + nw);

        __syncthreads();  // previous chunk's readers done
        As[kv + 0][m_l] = xv.x;
        As[kv + 1][m_l] = xv.y;
        As[kv + 2][m_l] = xv.z;
        As[kv + 3][m_l] = xv.w;
        *(float4*)&Bs[kw +  0][nw] = wv0;
        *(float4*)&Bs[kw +  4][nw] = wv1;
        *(float4*)&Bs[kw +  8][nw] = wv2;
        *(float4*)&Bs[kw + 12][nw] = wv3;
        __syncthreads();  // writes visible

#pragma unroll
        for (int k = 0; k < 16; k++) {
            float4 a0 = *(const float4*)&As[k][ty * 8];
            float4 a1 = *(const float4*)&As[k][ty * 8 + 4];
            float4 b0 = *(const float4*)&Bs[k][tx * 8];
            float4 b1 = *(const float4*)&Bs[k][tx * 8 + 4];
            float a[8] = {a0.x, a0.y, a0.z, a0.w, a1.x, a1.y, a1.z, a1.w};
            float b[8] = {b0.x, b0.y, b0.z, b0.w, b1.x, b1.y, b1.z, b1.w};
#pragma unroll
            for (int i = 0; i < 8; i++)
#pragma unroll
                for (int j = 0; j < 8; j++)
                    acc[i][j] = fmaf(a[i], b[j], acc[i][j]);
        }
    }

    // epilogue: + bias, store
    float bb[8];
#pragma unroll
    for (int j = 0; j < 8; j++) bb[j] = bh[tx * 8 + j];
#pragma unroll
    for (int i = 0; i < 8; i++) {
        size_t row = (size_t)(r0 + ty * 8 + i);
        float4 o0, o1;
        o0.x = acc[i][0] + bb[0]; o0.y = acc[i][1] + bb[1];
        o0.z = acc[i][2] + bb[2]; o0.w = acc[i][3] + bb[3];
        o1.x = acc[i][4] + bb[4]; o1.y = acc[i][5] + bb[5];
        o1.z = acc[i][6] + bb[6]; o1.w = acc[i][7] + bb[7];
        *(float4*)(out + row * 256 + tx * 8)     = o0;
        *(float4*)(out + row * 256 + tx * 8 + 4) = o1;
    }
}

// ---------------- Kernel B: sequential recurrence, 1 block per batch row ----
// 512 threads: h = tid&255 (output column), q = tid>>8 (k-chunk half).
// Thread holds W_hh[q*128 .. q*128+127][h] in 128 VGPRs.
__global__ __launch_bounds__(512) void rnn_rec(const float* __restrict__ Whh,
                                               float* __restrict__ out) {
    __shared__ float st[256];
    __shared__ float red[512];

    const int tid = threadIdx.x;
    const int h   = tid & 255;
    const int q   = tid >> 8;
    const int b   = blockIdx.x;

    float w[128];
#pragma unroll
    for (int i = 0; i < 128; i++)
        w[i] = Whh[(size_t)(q * 128 + i) * 256 + h];

    if (tid < 256) st[tid] = 0.f;

    float* outBase = out + (size_t)b * 256;  // element (t,b,h) at outBase[t*B*H + h]
    float xw_cur = 0.f, h_new = 0.f;
    if (tid < 256) xw_cur = outBase[h];      // t = 0 (kernel A completed: same stream)
    __syncthreads();

    for (int t = 0; t < TT; t++) {
        // prefetch next step's xw (covers global latency; t=1023 reads the
        // final-state region -> in-bounds garbage, never used)
        float xw_next = 0.f;
        if (tid < 256) xw_next = outBase[(size_t)(t + 1) * (BB * HH) + h];

        float acc = 0.f;
        const float* sp = st + q * 128;
#pragma unroll
        for (int i = 0; i < 128; i += 4) {
            float4 s4 = *(const float4*)(sp + i);  // wave-uniform broadcast read
            acc = fmaf(s4.x, w[i + 0], acc);
            acc = fmaf(s4.y, w[i + 1], acc);
            acc = fmaf(s4.z, w[i + 2], acc);
            acc = fmaf(s4.w, w[i + 3], acc);
        }
        red[tid] = acc;
        __syncthreads();  // all st reads + red writes done

        if (tid < 256) {
            float v = red[h] + red[h + 256] + xw_cur;
            h_new = tanhf(v);
            outBase[(size_t)t * (BB * HH) + h] = h_new;  // outputs[t,b,h]
            st[h] = h_new;
            xw_cur = xw_next;
        }
        __syncthreads();  // new state visible
    }

    if (tid < 256)
        out[(size_t)TT * BB * HH + (size_t)b * 256 + h] = h_new;  // final state
}

extern "C" void kernel_launch(void* const* d_in, const int* in_sizes, int n_in,
                              void* d_out, int out_size, void* d_ws, size_t ws_size,
                              hipStream_t stream) {
    const float* X   = (const float*)d_in[0];  // [T,B,I]
    const float* Wxh = (const float*)d_in[1];  // [I,H]
    const float* Whh = (const float*)d_in[2];  // [H,H]
    const float* bh  = (const float*)d_in[3];  // [H]
    float* out = (float*)d_out;

    xw_gemm<<<dim3((TT * BB) / 64), dim3(256), 0, stream>>>(X, Wxh, bh, out);
    rnn_rec<<<dim3(BB), dim3(512), 0, stream>>>(Whh, out);
}

// Round 2
// 1786.603 us; speedup vs baseline: 1.0381x; 1.0381x over previous
//
#include <hip/hip_runtime.h>

// T=1024, B=256, I=256, H=256, fp32 in/out.
// out = outputs [T,B,H] flat, then final state [B,H].
//
// Kernel A (unchanged): XW = X @ W_xh + b_h  -> out[0..T*B*H)
// Kernel B (NEW): MFMA recurrence. 64 blocks x 4 batch rows.
//   Rows placed at MFMA rows m in {0,4,8,12} => C reg0 of quad q = batch row q.
//   W_hh persistent in f16 B-fragments; state via padded LDS; xw in C operand.

#define TT 1024
#define BB 256
#define HH 256

typedef __attribute__((ext_vector_type(8))) _Float16 f16x8;
typedef __attribute__((ext_vector_type(4))) float f32x4;

// ---------------- Kernel A: [262144,256] @ [256,256] + bias ----------------
__global__ __launch_bounds__(256) void xw_gemm(const float* __restrict__ X,
                                               const float* __restrict__ W,
                                               const float* __restrict__ bh,
                                               float* __restrict__ out) {
    __shared__ float As[16][68];
    __shared__ float Bs[16][256];

    const int tid = threadIdx.x;
    const int r0  = blockIdx.x * 64;
    const int tx  = tid & 31;
    const int ty  = tid >> 5;

    const int m_l = tid >> 2;
    const int kv  = (tid & 3) * 4;
    const int nw  = (tid & 63) * 4;
    const int kw  = tid >> 6;

    float acc[8][8];
#pragma unroll
    for (int i = 0; i < 8; i++)
#pragma unroll
        for (int j = 0; j < 8; j++) acc[i][j] = 0.f;

    for (int kc = 0; kc < 256; kc += 16) {
        float4 xv  = *(const float4*)(X + (size_t)(r0 + m_l) * 256 + kc + kv);
        float4 wv0 = *(const float4*)(W + (size_t)(kc + kw +  0) * 256 + nw);
        float4 wv1 = *(const float4*)(W + (size_t)(kc + kw +  4) * 256 + nw);
        float4 wv2 = *(const float4*)(W + (size_t)(kc + kw +  8) * 256 + nw);
        float4 wv3 = *(const float4*)(W + (size_t)(kc + kw + 12) * 256 + nw);

        __syncthreads();
        As[kv + 0][m_l] = xv.x;
        As[kv + 1][m_l] = xv.y;
        As[kv + 2][m_l] = xv.z;
        As[kv + 3][m_l] = xv.w;
        *(float4*)&Bs[kw +  0][nw] = wv0;
        *(float4*)&Bs[kw +  4][nw] = wv1;
        *(float4*)&Bs[kw +  8][nw] = wv2;
        *(float4*)&Bs[kw + 12][nw] = wv3;
        __syncthreads();

#pragma unroll
        for (int k = 0; k < 16; k++) {
            float4 a0 = *(const float4*)&As[k][ty * 8];
            float4 a1 = *(const float4*)&As[k][ty * 8 + 4];
            float4 b0 = *(const float4*)&Bs[k][tx * 8];
            float4 b1 = *(const float4*)&Bs[k][tx * 8 + 4];
            float a[8] = {a0.x, a0.y, a0.z, a0.w, a1.x, a1.y, a1.z, a1.w};
            float b[8] = {b0.x, b0.y, b0.z, b0.w, b1.x, b1.y, b1.z, b1.w};
#pragma unroll
            for (int i = 0; i < 8; i++)
#pragma unroll
                for (int j = 0; j < 8; j++)
                    acc[i][j] = fmaf(a[i], b[j], acc[i][j]);
        }
    }

    float bb[8];
#pragma unroll
    for (int j = 0; j < 8; j++) bb[j] = bh[tx * 8 + j];
#pragma unroll
    for (int i = 0; i < 8; i++) {
        size_t row = (size_t)(r0 + ty * 8 + i);
        float4 o0, o1;
        o0.x = acc[i][0] + bb[0]; o0.y = acc[i][1] + bb[1];
        o0.z = acc[i][2] + bb[2]; o0.w = acc[i][3] + bb[3];
        o1.x = acc[i][4] + bb[4]; o1.y = acc[i][5] + bb[5];
        o1.z = acc[i][6] + bb[6]; o1.w = acc[i][7] + bb[7];
        *(float4*)(out + row * 256 + tx * 8)     = o0;
        *(float4*)(out + row * 256 + tx * 8 + 4) = o1;
    }
}

// ---------------- Kernel B: MFMA recurrence ----------------
__device__ __forceinline__ float fast_tanh(float x) {
    // tanh(x) = 1 - 2/(e^{2x}+1); exact limits at +-inf, |x| <= ~1.2 here.
    float e = __expf(2.0f * x);
    return 1.0f - 2.0f * __builtin_amdgcn_rcpf(e + 1.0f);
}

__global__ __launch_bounds__(256, 1) void rnn_rec_mfma(const float* __restrict__ Whh,
                                                       float* __restrict__ out) {
    // state rows: 4 real batch rows; +8 f16 pad -> consumer b128 reads 2-way (free)
    __shared__ alignas(16) _Float16 st[4][264];

    const int tid  = threadIdx.x;
    const int lane = tid & 63;
    const int wave = tid >> 6;        // N slice [wave*64, wave*64+64)
    const int c    = lane & 15;       // col-in-tile (B n, C col, A m)
    const int quad = lane >> 4;       // 0..3
    const int b0   = blockIdx.x * 4;  // batch rows b0..b0+3 at m = 4*r

    // ---- persistent B fragments: bf[nt][kt][j] = W_hh[kt*32+quad*8+j][wave*64+nt*16+c]
    f16x8 bf[4][8];
#pragma unroll
    for (int nt = 0; nt < 4; nt++) {
        const int n = wave * 64 + nt * 16 + c;
#pragma unroll
        for (int kt = 0; kt < 8; kt++) {
            const int kb = kt * 32 + quad * 8;
            f16x8 v;
#pragma unroll
            for (int j = 0; j < 8; j++)
                v[j] = (_Float16)Whh[(size_t)(kb + j) * HH + n];
            bf[nt][kt] = v;
        }
    }

    // zero initial state
    for (int i = tid; i < 4 * 264; i += 256)
        ((_Float16*)st)[i] = (_Float16)0.f;

    const int  m       = c;               // A-row this lane serves
    const bool realrow = ((m & 3) == 0);
    const int  r       = m >> 2;          // batch row for real A lanes

    // xw element (t, b0+quad, wave*64+nt*16+c)
    const size_t colbase = (size_t)(b0 + quad) * HH + wave * 64 + c;
    float xw_c[4], xw_n[4], xw_p[4];
#pragma unroll
    for (int nt = 0; nt < 4; nt++) xw_c[nt] = out[colbase + nt * 16];                       // t=0
#pragma unroll
    for (int nt = 0; nt < 4; nt++) xw_n[nt] = out[(size_t)BB * HH + colbase + nt * 16];     // t=1
    __syncthreads();  // st zero-init visible

    float h[4] = {0.f, 0.f, 0.f, 0.f};

    for (int t = 0; t < TT; t++) {
        // A fragments from LDS (exec-masked: fake rows are constant zero)
        f16x8 af[8];
        if (realrow) {
#pragma unroll
            for (int kt = 0; kt < 8; kt++)
                af[kt] = *(const f16x8*)&st[r][kt * 32 + quad * 8];
        } else {
#pragma unroll
            for (int kt = 0; kt < 8; kt++) af[kt] = (f16x8)(_Float16)0.f;
        }

        // prefetch xw for t+2 (covers HBM latency across one full step)
        {
            const int tp = (t + 2 > TT - 1) ? (TT - 1) : (t + 2);
#pragma unroll
            for (int nt = 0; nt < 4; nt++)
                xw_p[nt] = out[(size_t)tp * (BB * HH) + colbase + nt * 16];
        }

        __syncthreads();  // B1: all st reads complete before overwrite

        f32x4 acc[4];
#pragma unroll
        for (int nt = 0; nt < 4; nt++) acc[nt] = (f32x4){xw_c[nt], 0.f, 0.f, 0.f};
#pragma unroll
        for (int kt = 0; kt < 8; kt++)
#pragma unroll
            for (int nt = 0; nt < 4; nt++)
                acc[nt] = __builtin_amdgcn_mfma_f32_16x16x32_f16(af[kt], bf[nt][kt], acc[nt], 0, 0, 0);

        // epilogue: reg0 of quad q = batch row q (real rows at m=4q)
        const size_t obase = (size_t)t * (BB * HH) + colbase;
#pragma unroll
        for (int nt = 0; nt < 4; nt++) {
            h[nt] = fast_tanh(acc[nt][0]);
            out[obase + nt * 16] = h[nt];
            st[quad][wave * 64 + nt * 16 + c] = (_Float16)h[nt];
        }
#pragma unroll
        for (int nt = 0; nt < 4; nt++) { xw_c[nt] = xw_n[nt]; xw_n[nt] = xw_p[nt]; }

        __syncthreads();  // B2: new state visible to next step's readers
    }

    const size_t fbase = (size_t)TT * (BB * HH) + colbase;
#pragma unroll
    for (int nt = 0; nt < 4; nt++) out[fbase + nt * 16] = h[nt];
}

extern "C" void kernel_launch(void* const* d_in, const int* in_sizes, int n_in,
                              void* d_out, int out_size, void* d_ws, size_t ws_size,
                              hipStream_t stream) {
    const float* X   = (const float*)d_in[0];  // [T,B,I]
    const float* Wxh = (const float*)d_in[1];  // [I,H]
    const float* Whh = (const float*)d_in[2];  // [H,H]
    const float* bh  = (const float*)d_in[3];  // [H]
    float* out = (float*)d_out;

    xw_gemm<<<dim3((TT * BB) / 64), dim3(256), 0, stream>>>(X, Wxh, bh, out);
    rnn_rec_mfma<<<dim3(BB / 4), dim3(256), 0, stream>>>(Whh, out);
}